// Round 1
// baseline (1256.162 us; speedup 1.0000x reference)
//
#include <hip/hip_runtime.h>

// OctreeMaxUnpool: out[i*8 + c, k] = (indices[i,k] == c) ? data[nempty_idx[i], k] : 0
// num = 500000, C = 64, NUM_CHILDREN = 8. Output: [num*8, C] fp32 = 1.024 GB.
// Memory-write-bound: one thread per output float4 (16 B/lane coalesced stores).

constexpr int C = 64;        // channels (rows are 256 B -> float4/int4 aligned)
constexpr int NCHILD = 8;    // octree children
// per-i output = 8*64 = 512 floats = 128 float4  -> g>>7 = i, g&127 = r
// r: child = r>>4 (16 float4 per child row), k4 = r&15

__global__ __launch_bounds__(256) void octree_unpool_kernel(
    const float* __restrict__ data,      // [N, 64]
    const int*   __restrict__ indices,   // [num, 64], values 0..7
    const int*   __restrict__ nempty,    // [num]
    float*       __restrict__ out,       // [num*8, 64]
    int num)
{
    long long g = (long long)blockIdx.x * blockDim.x + threadIdx.x;
    long long total = (long long)num * (NCHILD * C / 4);
    if (g >= total) return;

    int i     = (int)(g >> 7);
    int r     = (int)(g & 127);
    int child = r >> 4;
    int k4    = r & 15;

    int row = nempty[i];  // uniform across the 128 threads of this i -> L1 broadcast

    const int4*   idxp = (const int4*)  (indices + (long long)i   * C);
    const float4* dp   = (const float4*)(data    + (long long)row * C);

    int4   idx4 = idxp[k4];
    float4 d4   = dp[k4];

    float4 o;
    o.x = (idx4.x == child) ? d4.x : 0.0f;
    o.y = (idx4.y == child) ? d4.y : 0.0f;
    o.z = (idx4.z == child) ? d4.z : 0.0f;
    o.w = (idx4.w == child) ? d4.w : 0.0f;

    ((float4*)out)[g] = o;
}

extern "C" void kernel_launch(void* const* d_in, const int* in_sizes, int n_in,
                              void* d_out, int out_size, void* d_ws, size_t ws_size,
                              hipStream_t stream) {
    const float* data    = (const float*)d_in[0];
    const int*   indices = (const int*)  d_in[1];
    const int*   nempty  = (const int*)  d_in[2];
    // d_in[3] = depth (unused)
    float* out = (float*)d_out;

    int num = in_sizes[2];                       // 500000
    long long total = (long long)num * (NCHILD * C / 4);  // float4 count
    int block = 256;
    long long grid = (total + block - 1) / block;

    octree_unpool_kernel<<<(dim3)(unsigned)grid, block, 0, stream>>>(
        data, indices, nempty, out, num);
}

// Round 3
// 1182.299 us; speedup vs baseline: 1.0625x; 1.0625x over previous
//
#include <hip/hip_runtime.h>

// OctreeMaxUnpool: out[i*8 + c, k] = (indices[i,k] == c) ? data[nempty_idx[i], k] : 0
// num = 500000, C = 64. Output [num*8, 64] fp32 = 1.024 GB -> write-bound.
//
// R3: same structure as R2 (one thread per (i, k4-chunk); each input element
// loaded exactly once; 8 non-temporal child stores), with Clang native vector
// types so __builtin_nontemporal_* compiles (HIP_vector_type structs are
// rejected by the builtin).

typedef float vfloat4 __attribute__((ext_vector_type(4)));
typedef int   vint4   __attribute__((ext_vector_type(4)));

constexpr int C4 = 16;      // float4s per row (C=64)
constexpr int NCHILD = 8;

__global__ __launch_bounds__(256) void octree_unpool_kernel(
    const vfloat4* __restrict__ data,      // [N, 16] as float4
    const vint4*   __restrict__ indices,   // [num, 16] as int4
    const int*     __restrict__ nempty,    // [num]
    vfloat4*       __restrict__ out,       // [num*8, 16] as float4
    int num)
{
    int t = blockIdx.x * blockDim.x + threadIdx.x;
    int total = num * C4;                 // 8M threads
    if (t >= total) return;

    int i  = t >> 4;        // octant group
    int k4 = t & 15;        // float4 chunk within row

    int row = nempty[i];    // 16 threads share -> 4 distinct addrs/wave

    vint4   idx4 = __builtin_nontemporal_load(&indices[i * C4 + k4]);
    vfloat4 d4   = data[(long long)row * C4 + k4];

    vfloat4* base = out + (long long)i * (NCHILD * C4) + k4;

#pragma unroll
    for (int c = 0; c < NCHILD; ++c) {
        vfloat4 o;
        o.x = (idx4.x == c) ? d4.x : 0.0f;
        o.y = (idx4.y == c) ? d4.y : 0.0f;
        o.z = (idx4.z == c) ? d4.z : 0.0f;
        o.w = (idx4.w == c) ? d4.w : 0.0f;
        __builtin_nontemporal_store(o, base + c * C4);
    }
}

extern "C" void kernel_launch(void* const* d_in, const int* in_sizes, int n_in,
                              void* d_out, int out_size, void* d_ws, size_t ws_size,
                              hipStream_t stream) {
    const vfloat4* data    = (const vfloat4*)d_in[0];
    const vint4*   indices = (const vint4*)  d_in[1];
    const int*     nempty  = (const int*)    d_in[2];
    // d_in[3] = depth (unused)
    vfloat4* out = (vfloat4*)d_out;

    int num = in_sizes[2];                 // 500000
    int total = num * C4;                  // one thread per (i, k4)
    int block = 256;
    int grid = (total + block - 1) / block;

    octree_unpool_kernel<<<grid, block, 0, stream>>>(data, indices, nempty, out, num);
}